// Round 5
// baseline (405.742 us; speedup 1.0000x reference)
//
#include <hip/hip_runtime.h>
#include <cmath>
#include <climits>

#define EMBED 64
#define KTOP 11          // top_n + 1 (self match included, dropped at output)
#define NB   512         // pass1 blocks: 2/CU x 256 CU, all resident
#define BLOCK1 256       // 4 waves
#define NW1  (BLOCK1 / 64)
#define BLOCK2 256
#define NW2  (BLOCK2 / 64)

// Insert (v,i) into per-thread sorted top-KTOP list (desc value, asc index).
__device__ __forceinline__ void topk_insert(float (&vals)[KTOP], int (&idxs)[KTOP],
                                            float v, int i) {
  float last = vals[KTOP - 1];
  if (v < last) return;
  if (v == last && i >= idxs[KTOP - 1]) return;
  float cv = v; int ci = i;
#pragma unroll
  for (int j = 0; j < KTOP; ++j) {
    bool better = (cv > vals[j]) || (cv == vals[j] && ci < idxs[j]);
    if (better) {
      float tv = vals[j]; int ti = idxs[j];
      vals[j] = cv; idxs[j] = ci;
      cv = tv; ci = ti;
    }
  }
}

// Merge 64 lanes' sorted top-KTOP lists into wave top-KTOP, written to LDS.
__device__ __forceinline__ void wave_merge(float (&vals)[KTOP], int (&idxs)[KTOP],
                                           float* wv, int* wi, int lane) {
#pragma unroll
  for (int round = 0; round < KTOP; ++round) {
    float v = vals[0]; int i = idxs[0]; int l = lane;
#pragma unroll
    for (int off = 32; off > 0; off >>= 1) {
      float ov = __shfl_xor(v, off, 64);
      int   oi = __shfl_xor(i, off, 64);
      int   ol = __shfl_xor(l, off, 64);
      if (ov > v || (ov == v && oi < i)) { v = ov; i = oi; l = ol; }
    }
    if (l == lane) {  // winner pops its head
#pragma unroll
      for (int j = 0; j < KTOP - 1; ++j) { vals[j] = vals[j + 1]; idxs[j] = idxs[j + 1]; }
      vals[KTOP - 1] = -INFINITY; idxs[KTOP - 1] = INT_MAX;
    }
    if (lane == 0) { wv[round] = v; wi[round] = i; }
  }
}

__global__ __launch_bounds__(BLOCK1, 2) void sim_pass1(
    const float* __restrict__ emb, const int* __restrict__ user_id,
    float* __restrict__ cand_val, int* __restrict__ cand_idx, int V) {
  __shared__ float wv[NW1 * KTOP];
  __shared__ int   wi[NW1 * KTOP];

  const int lane = threadIdx.x & 63;
  const int wid  = threadIdx.x >> 6;
  const int uid  = *user_id;

  // In the contiguous-tile layout, lane l always holds chunk (l & 15).
  const float4 tgt = ((const float4*)(emb + (size_t)uid * EMBED))[lane & 15];

  float vals[KTOP]; int idxs[KTOP];
#pragma unroll
  for (int j = 0; j < KTOP; ++j) { vals[j] = -INFINITY; idxs[j] = INT_MAX; }

  const int gw = blockIdx.x * NW1 + wid;
  const int nW = NB * NW1;
  const int nTiles = (V + 63) >> 6;          // 64 rows (16 KB) per tile
  const float4* base = (const float4*)emb;   // table as float4 units
  const size_t maxQ = (size_t)V * 16 - 1;    // last valid float4 index

  for (int tile = gw; tile < nTiles; tile += nW) {
    // ---- load 16 KB tile: 16 contiguous 1 KB wave-instructions ----
    const size_t q0 = (size_t)tile * 1024 + lane;
    float4 v[16];
#pragma unroll
    for (int j = 0; j < 16; ++j) {
      size_t q = q0 + (size_t)j * 64;
      if (q > maxQ) q = maxQ;   // only clamps in a ragged last tile; those
      v[j] = base[q];           // partials belong to rows >= V -> discarded
    }

    // ---- per-lane partials: segment j is row tile*64 + j*4 + (lane>>4),
    //      chunk (lane&15). d[j]/n[j] = this lane's chunk contribution. ----
    float d[16], n[16];
#pragma unroll
    for (int j = 0; j < 16; ++j) {
      float4 x = v[j];
      float dd =        x.x * tgt.x;
      dd = fmaf(x.y, tgt.y, dd); dd = fmaf(x.z, tgt.z, dd); dd = fmaf(x.w, tgt.w, dd);
      float nn =        x.x * x.x;
      nn = fmaf(x.y, x.y, nn);   nn = fmaf(x.z, x.z, nn);   nn = fmaf(x.w, x.w, nn);
      d[j] = dd; n[j] = nn;
    }

    // ---- reduce-scatter across the 16-lane group (xor 1,2,4,8):
    //      after 4 halving stages, d[0]/n[0] on lane l are the full sums for
    //      value index t = l&15, i.e. row tile*64 + (l&15)*4 + (l>>4). ----
#pragma unroll
    for (int st = 0; st < 4; ++st) {
      const int m = 1 << st;
      const int b = (lane >> st) & 1;
#pragma unroll
      for (int k = 0; k < (16 >> (st + 1)); ++k) {
        float dk = b ? d[2 * k + 1] : d[2 * k];
        float ds = b ? d[2 * k]     : d[2 * k + 1];
        float nk = b ? n[2 * k + 1] : n[2 * k];
        float ns = b ? n[2 * k]     : n[2 * k + 1];
        d[k] = dk + __shfl_xor(ds, m, 64);
        n[k] = nk + __shfl_xor(ns, m, 64);
      }
    }

    const int r = (tile << 6) + ((lane & 15) << 2) + (lane >> 4);
    if (r < V)
      topk_insert(vals, idxs, d[0] / sqrtf(n[0]), r);  // /||target|| deferred
  }

  wave_merge(vals, idxs, &wv[wid * KTOP], &wi[wid * KTOP], lane);
  __syncthreads();

  if (wid == 0) {  // wave 0 merges NW1*KTOP entries -> block top-KTOP
    float v = (lane < NW1 * KTOP) ? wv[lane] : -INFINITY;
    int   i = (lane < NW1 * KTOP) ? wi[lane] : INT_MAX;
#pragma unroll
    for (int round = 0; round < KTOP; ++round) {
      float bv = v; int bi = i; int bl = lane;
#pragma unroll
      for (int off = 32; off > 0; off >>= 1) {
        float ov = __shfl_xor(bv, off, 64);
        int   oi = __shfl_xor(bi, off, 64);
        int   ol = __shfl_xor(bl, off, 64);
        if (ov > bv || (ov == bv && oi < bi)) { bv = ov; bi = oi; bl = ol; }
      }
      if (bl == lane) { v = -INFINITY; i = INT_MAX; }
      if (lane == 0) {
        cand_val[blockIdx.x * KTOP + round] = bv;
        cand_idx[blockIdx.x * KTOP + round] = bi;
      }
    }
  }
}

__global__ __launch_bounds__(BLOCK2) void sim_pass2(
    const float* __restrict__ emb, const int* __restrict__ user_id,
    const float* __restrict__ cand_val, const int* __restrict__ cand_idx,
    float* __restrict__ out, int topn, int ncand) {
  __shared__ float wv[NW2 * KTOP];
  __shared__ int   wi[NW2 * KTOP];
  __shared__ float s_nt;

  const int lane = threadIdx.x & 63;
  const int wid  = threadIdx.x >> 6;

  if (wid == 0) {  // ||target|| on wave 0
    const int uid = *user_id;
    float x = (lane < EMBED) ? emb[(size_t)uid * EMBED + lane] : 0.f;
    float s = x * x;
#pragma unroll
    for (int off = 32; off > 0; off >>= 1) s += __shfl_xor(s, off, 64);
    if (lane == 0) s_nt = sqrtf(s);
  }

  float vals[KTOP]; int idxs[KTOP];
#pragma unroll
  for (int j = 0; j < KTOP; ++j) { vals[j] = -INFINITY; idxs[j] = INT_MAX; }

  for (int c = threadIdx.x; c < ncand; c += BLOCK2)
    topk_insert(vals, idxs, cand_val[c], cand_idx[c]);

  wave_merge(vals, idxs, &wv[wid * KTOP], &wi[wid * KTOP], lane);
  __syncthreads();

  if (wid == 0) {
    float v = (lane < NW2 * KTOP) ? wv[lane] : -INFINITY;
    int   i = (lane < NW2 * KTOP) ? wi[lane] : INT_MAX;
    const float nt = s_nt;
#pragma unroll
    for (int round = 0; round < KTOP; ++round) {
      float bv = v; int bi = i; int bl = lane;
#pragma unroll
      for (int off = 32; off > 0; off >>= 1) {
        float ov = __shfl_xor(bv, off, 64);
        int   oi = __shfl_xor(bi, off, 64);
        int   ol = __shfl_xor(bl, off, 64);
        if (ov > bv || (ov == bv && oi < bi)) { bv = ov; bi = oi; bl = ol; }
      }
      if (bl == lane) { v = -INFINITY; i = INT_MAX; }
      // round 0 is the self match -> dropped (matches ref's top_vals[1:])
      if (lane == 0 && round >= 1 && round <= topn) {
        out[round - 1]        = bv / nt;       // similarity value
        out[topn + round - 1] = (float)bi;     // index, as float
      }
    }
  }
}

extern "C" void kernel_launch(void* const* d_in, const int* in_sizes, int n_in,
                              void* d_out, int out_size, void* d_ws, size_t ws_size,
                              hipStream_t stream) {
  const float* emb = (const float*)d_in[0];
  const int*   uid = (const int*)d_in[1];
  const int V    = in_sizes[0] / EMBED;
  const int topn = out_size / 2;  // 10 -> KTOP = 11 covers it

  float* cand_val = (float*)d_ws;
  int*   cand_idx = (int*)((char*)d_ws + (size_t)NB * KTOP * sizeof(float));

  sim_pass1<<<NB, BLOCK1, 0, stream>>>(emb, uid, cand_val, cand_idx, V);
  sim_pass2<<<1, BLOCK2, 0, stream>>>(emb, uid, cand_val, cand_idx,
                                      (float*)d_out, topn, NB * KTOP);
}